// Round 8
// baseline (214.850 us; speedup 1.0000x reference)
//
#include <hip/hip_runtime.h>
#include <hip/hip_bf16.h>
#include <stdint.h>

#define B_  4
#define S_  2048
#define D_  1024
#define H_  1024
#define BS_ (B_*S_)    // 8192
#define N3H (3*H_)     // 3072

typedef __bf16 bf16x8 __attribute__((ext_vector_type(8)));
typedef float  f32x4  __attribute__((ext_vector_type(4)));
typedef unsigned short u16x8 __attribute__((ext_vector_type(8)));

__device__ __forceinline__ unsigned short f2bf(float x) {
    unsigned u = __float_as_uint(x);
    return (unsigned short)((u + 0x7FFFu + ((u >> 16) & 1u)) >> 16);  // RNE
}
__device__ __forceinline__ float bf2f(unsigned short h) {
    return __uint_as_float(((unsigned)h) << 16);
}

__device__ __forceinline__ void gload_lds16(const void* g, void* l) {
    __builtin_amdgcn_global_load_lds(
        (const __attribute__((address_space(1))) void*)g,
        (__attribute__((address_space(3))) void*)l, 16, 0, 0);
}

#define BAR __builtin_amdgcn_s_barrier()
#define DS_FENCE do { asm volatile("s_waitcnt lgkmcnt(0)" ::: "memory"); \
                      __builtin_amdgcn_sched_barrier(0); } while (0)

// ---------------------------------------------------------------------------
// gemm3b: 128x128-tile bt-GEMM, BK=32, 256 threads (2x2 waves, wave 64x64,
// acc 4x4), triple-buffered 48 KiB LDS, 3 blocks/CU. st_16x32 swizzle.
// Core loop verified rounds 6-7.
// EPI 0: QKV split: q,k (+bias b1); u-segment (cols 2048+) written TRANSPOSED
//        (no bias -- bias algebraically moved to final epilogue via bu2).
// EPI 1: bf16 out * scale (used for the wu = w2t @ w1v^T precompute)
// EPI 5: FINAL: f32 out = acc / l[row] + bu2[col]  (l via `bias`, bu2 via out1)
// SWZ 0: plain tile=bid mapping (small grids); SWZ 1: XCD-chunked + 2D suborder
// ---------------------------------------------------------------------------
template<int EPI, int SWZ>
__global__ __launch_bounds__(256, 3) void gemm3b(
    const unsigned short* __restrict__ A,
    const unsigned short* __restrict__ Bm,
    int NXt, int NYt, int N, int K,
    long long sAz, long long sBz, long long sOz,
    void* __restrict__ out0, void* __restrict__ out1, void* __restrict__ out2,
    const float* __restrict__ bias, float scale)
{
    __shared__ __align__(16) char lds[3 * 16384];

    const int bid = (int)blockIdx.x;
    int tile;
    if constexpr (SWZ) {
        const int nt_g = (int)gridDim.x;
        const int C = nt_g >> 3;
        const int c = bid >> 3;
        const int xcd = bid & 7;
        const int qq = c >> 2;
        const int txl = qq % NXt;
        const int rest = (c & 3) + 4 * (qq / NXt);
        tile = xcd * C + rest * NXt + txl;
    } else {
        tile = bid;
    }
    const int tx = tile % NXt;
    const int rest2 = tile / NXt;
    const int ty = rest2 % NYt;
    const int tz = rest2 / NYt;

    const unsigned short* Ab = A  + (long long)tz * sAz;
    const unsigned short* Bb = Bm + (long long)tz * sBz;
    const int rowBase = ty * 128;
    const int colBase = tx * 128;
    const int tid = threadIdx.x;
    const int w = tid >> 6, l = tid & 63;
    const int wr = w >> 1, wc = w & 1;          // 2M x 2N waves
    const int fr = l & 15, fq = l >> 4;

    // staging source decode (inverse st_16x32 swizzle)
    int sr[2], scl[2];
#pragma unroll
    for (int j = 0; j < 2; j++) {
        int o  = j * 4096 + tid * 16;
        int st = o >> 10;
        int wi = o & 1023;
        wi ^= ((wi >> 9) & 1) << 5;
        sr[j]  = st * 16 + (wi >> 6);
        scl[j] = (wi & 63) >> 1;
    }

    auto STAGE_A = [&](char* buf, int t) {
        const unsigned short* base = Ab + (long long)rowBase * K + t * 32;
#pragma unroll
        for (int j = 0; j < 2; j++)
            gload_lds16(base + (long long)sr[j] * K + scl[j],
                        buf + j * 4096 + w * 1024);
    };
    auto STAGE_B = [&](char* buf, int t) {
        const unsigned short* base = Bb + (long long)colBase * K + t * 32;
#pragma unroll
        for (int j = 0; j < 2; j++)
            gload_lds16(base + (long long)sr[j] * K + scl[j],
                        buf + 8192 + j * 4096 + w * 1024);
    };

    const int abase = (fr * 64 + fq * 16) ^ ((fr & 8) << 2);

    f32x4 acc[4][4];
#pragma unroll
    for (int m = 0; m < 4; m++)
#pragma unroll
        for (int n = 0; n < 4; n++) acc[m][n] = (f32x4){0.f, 0.f, 0.f, 0.f};

    const int NT = K >> 5;

    STAGE_A(lds, 0); STAGE_B(lds, 0);
    STAGE_A(lds + 16384, 1); STAGE_B(lds + 16384, 1);
    asm volatile("s_waitcnt vmcnt(4)" ::: "memory");
    BAR;
    __builtin_amdgcn_sched_barrier(0);

    bf16x8 af[4], bf[4];

    for (int t = 0; t < NT; ++t) {
        const char* bc = lds + (t % 3) * 16384;
        char* bs = lds + ((t + 2) % 3) * 16384;
        int ts = t + 2; if (ts >= NT) ts -= NT;

#pragma unroll
        for (int m = 0; m < 4; m++)
            af[m] = *(const bf16x8*)(bc + (wr * 4 + m) * 1024 + abase);
#pragma unroll
        for (int n = 0; n < 4; n++)
            bf[n] = *(const bf16x8*)(bc + 8192 + (wc * 4 + n) * 1024 + abase);
        STAGE_A(bs, ts); STAGE_B(bs, ts);
        BAR; DS_FENCE;
        __builtin_amdgcn_s_setprio(1);
#pragma unroll
        for (int m = 0; m < 4; m++)
#pragma unroll
            for (int n = 0; n < 4; n++)
                acc[m][n] = __builtin_amdgcn_mfma_f32_16x16x32_bf16(
                    af[m], bf[n], acc[m][n], 0, 0, 0);
        __builtin_amdgcn_s_setprio(0);
        asm volatile("s_waitcnt vmcnt(4)" ::: "memory");
        BAR;
        __builtin_amdgcn_sched_barrier(0);
    }

    asm volatile("s_waitcnt vmcnt(0) lgkmcnt(0)" ::: "memory");
    BAR;   // all waves' in-flight DMA landed -> LDS reusable below

    const int crow0 = rowBase + wr * 64 + fq * 4;
    const int ccol0 = colBase + wc * 64 + fr;

    if constexpr (EPI == 0) {
        const int seg = colBase >> 10;           // block is column-aligned
        if (seg < 2) {
            unsigned short* dst = (unsigned short*)(seg == 0 ? out0 : out1);
#pragma unroll
            for (int n = 0; n < 4; n++) {
                const int col = ccol0 + n * 16;
                const float bv = bias[col];
                const int scn = col & 1023;
#pragma unroll
                for (int m = 0; m < 4; m++) {
                    const int r0 = crow0 + m * 16;
#pragma unroll
                    for (int j = 0; j < 4; j++)
                        dst[(long long)(r0 + j) * 1024 + scn] = f2bf(acc[m][n][j] + bv);
                }
            }
        } else {
            // u segment: stage into LDS [128][129], write transposed -> ut[b][h][s]
            unsigned short (*T)[129] = (unsigned short(*)[129])lds;
            const int lr0 = wr * 64 + fq * 4;
            const int lc0 = wc * 64 + fr;
#pragma unroll
            for (int n = 0; n < 4; n++) {
                const int lc = lc0 + n * 16;
#pragma unroll
                for (int m = 0; m < 4; m++)
#pragma unroll
                    for (int j = 0; j < 4; j++)
                        T[lr0 + m * 16 + j][lc] = f2bf(acc[m][n][j]);
            }
            BAR;
            const int s_loc = tid & 127, hh = tid >> 7;
            const int b = rowBase >> 11;
            const int s_glob = (rowBase & 2047) + s_loc;
            unsigned short* ut =
                (unsigned short*)out2 + (long long)b * ((long long)S_ * H_);
            const int h0 = (colBase - 2048) + hh * 64;
#pragma unroll 8
            for (int h = 0; h < 64; ++h)
                ut[(long long)(h0 + h) * S_ + s_glob] = T[s_loc][hh * 64 + h];
        }
    } else if constexpr (EPI == 1) {
        unsigned short* dst = (unsigned short*)out0 + (long long)tz * sOz;
#pragma unroll
        for (int n = 0; n < 4; n++) {
            const int col = ccol0 + n * 16;
#pragma unroll
            for (int m = 0; m < 4; m++) {
                const int r0 = crow0 + m * 16;
#pragma unroll
                for (int j = 0; j < 4; j++)
                    dst[(long long)(r0 + j) * N + col] = f2bf(acc[m][n][j] * scale);
            }
        }
    } else {
        // EPI 5: final output: f32 = acc / l[row] + bu2[col]
        float* dst = (float*)out0 + (long long)tz * sOz;
        const float* bu = (const float*)out1;
#pragma unroll
        for (int m = 0; m < 4; m++) {
            float linv[4];
#pragma unroll
            for (int j = 0; j < 4; j++)
                linv[j] = 1.0f / bias[tz * 2048 + crow0 + m * 16 + j];
#pragma unroll
            for (int n = 0; n < 4; n++) {
                const int col = ccol0 + n * 16;
                const float bvv = bu[col];
                const int r0 = crow0 + m * 16;
#pragma unroll
                for (int j = 0; j < 4; j++)
                    dst[(long long)(r0 + j) * N + col] = acc[m][n][j] * linv[j] + bvv;
            }
        }
        (void)scale;
    }
}

// ---------------------------------------------------------------------------
// gemm256: 256x256 8-phase kernel, XCD-chunked 1D grid. EPI=2 epilogue:
// P~ = exp(acc*scale) bf16; per-row l via shfl-reduce + atomicAdd (out1).
// Verified round 7.
// ---------------------------------------------------------------------------
template<int EPI>
__global__ __launch_bounds__(512, 2) void gemm256(
    const unsigned short* __restrict__ A,
    const unsigned short* __restrict__ Bm,
    int NXt, int NYt, int N, int K,
    long long sAz, long long sBz, long long sOz,
    void* __restrict__ out0, void* __restrict__ out1, void* __restrict__ out2,
    const float* __restrict__ bias, float scale)
{
    __shared__ __align__(16) char lds[131072];

    const int nt_g = (int)gridDim.x;
    const int bid = (int)blockIdx.x;
    const int C = nt_g >> 3;
    const int c = bid >> 3;
    const int xcd = bid & 7;
    const int qq = c >> 2;
    const int txl = qq % NXt;
    const int rest = (c & 3) + 4 * (qq / NXt);
    const int tile = xcd * C + rest * NXt + txl;
    const int tx = tile % NXt;
    const int rest2 = tile / NXt;
    const int ty = rest2 % NYt;
    const int tz = rest2 / NYt;

    const unsigned short* Ab = A  + (long long)tz * sAz;
    const unsigned short* Bb = Bm + (long long)tz * sBz;
    const int rowBase = ty * 256;
    const int colBase = tx * 256;
    const int tid = threadIdx.x;
    const int w = tid >> 6, l = tid & 63;
    const int wr = w >> 2, wc = w & 3;
    const int fr = l & 15, fq = l >> 4;

    int sr[2], scl[2];
#pragma unroll
    for (int j = 0; j < 2; j++) {
        int o  = j * 8192 + tid * 16;
        int st = o >> 10;
        int wi = o & 1023;
        wi ^= ((wi >> 9) & 1) << 5;
        sr[j]  = (st >> 1) * 16 + (wi >> 6);
        scl[j] = (st & 1) * 32 + ((wi & 63) >> 1);
    }

    auto STAGE = [&](int buf, int which, int tile_) {
        const unsigned short* mat = (which < 2) ? Ab : Bb;
        const int rt0 = ((which < 2) ? rowBase : colBase) + (which & 1) * 128;
        char* dst = lds + buf * 65536 + (which >> 1) * 32768
                        + (which & 1) * 16384 + w * 1024;
        const int k0 = tile_ * 64;
#pragma unroll
        for (int j = 0; j < 2; j++) {
            const unsigned short* src =
                mat + (long long)(rt0 + sr[j]) * K + k0 + scl[j];
            gload_lds16(src, dst + j * 8192);
        }
    };

    const int abase = (fr * 64 + fq * 16) ^ ((fr & 8) << 2);
    const char* Ah[2] = { lds + wr * 16384, lds + 65536 + wr * 16384 };
    const char* Bh[2] = { lds + 32768 + (wc >> 1) * 16384,
                          lds + 98304 + (wc >> 1) * 16384 };
    const int bn0 = (wc & 1) * 8192;

#define LA(b, m, kk) (*(const bf16x8*)(Ah[b] + (m)*2048 + (kk)*1024 + abase))
#define LB(b, n, kk) (*(const bf16x8*)(Bh[b] + bn0 + (n)*2048 + (kk)*1024 + abase))
#define MFMA16(AF, BF, MOFF, NOFF) do { \
    __builtin_amdgcn_s_setprio(1); \
    _Pragma("unroll") for (int m_ = 0; m_ < 4; m_++) \
    _Pragma("unroll") for (int n_ = 0; n_ < 2; n_++) \
    _Pragma("unroll") for (int k_ = 0; k_ < 2; k_++) \
        acc[(MOFF)+m_][(NOFF)+n_] = __builtin_amdgcn_mfma_f32_16x16x32_bf16( \
            AF[m_][k_], BF[n_][k_], acc[(MOFF)+m_][(NOFF)+n_], 0, 0, 0); \
    __builtin_amdgcn_s_setprio(0); } while (0)

    f32x4 acc[8][4];
#pragma unroll
    for (int m = 0; m < 8; m++)
#pragma unroll
        for (int n = 0; n < 4; n++) acc[m][n] = (f32x4){0.f, 0.f, 0.f, 0.f};

    const int NT = K >> 6;

    STAGE(0, 0, 0); STAGE(0, 1, 0); STAGE(0, 2, 0); STAGE(0, 3, 0);
    STAGE(1, 0, 1); STAGE(1, 1, 1);
    asm volatile("s_waitcnt vmcnt(4)" ::: "memory");
    BAR;
    __builtin_amdgcn_sched_barrier(0);

    bf16x8 afA[4][2], afB[4][2], bfA[2][2], bfB[2][2];

    for (int i = 0; i < NT / 2; i++) {
        const int t1 = 2 * i + 1;
        int t2 = 2 * i + 2; if (t2 >= NT) t2 -= NT;
        int t3 = 2 * i + 3; if (t3 >= NT) t3 -= NT;

#pragma unroll
        for (int m = 0; m < 4; m++) { afA[m][0] = LA(0, m, 0); afA[m][1] = LA(0, m, 1); }
#pragma unroll
        for (int n = 0; n < 2; n++) { bfA[n][0] = LB(0, n, 0); bfA[n][1] = LB(0, n, 1); }
        STAGE(1, 2, t1);
        BAR; DS_FENCE;
        MFMA16(afA, bfA, 0, 0);
        BAR;
#pragma unroll
        for (int m = 0; m < 4; m++) { afB[m][0] = LA(0, 4 + m, 0); afB[m][1] = LA(0, 4 + m, 1); }
        STAGE(1, 3, t1);
        BAR; DS_FENCE;
        MFMA16(afB, bfA, 4, 0);
        BAR;
#pragma unroll
        for (int n = 0; n < 2; n++) { bfB[n][0] = LB(0, 2 + n, 0); bfB[n][1] = LB(0, 2 + n, 1); }
        STAGE(0, 0, t2);
        BAR; DS_FENCE;
        MFMA16(afA, bfB, 0, 2);
        BAR;
        STAGE(0, 1, t2);
        BAR;
        MFMA16(afB, bfB, 4, 2);
        asm volatile("s_waitcnt vmcnt(4)" ::: "memory");
        BAR;
        __builtin_amdgcn_sched_barrier(0);

#pragma unroll
        for (int m = 0; m < 4; m++) { afA[m][0] = LA(1, m, 0); afA[m][1] = LA(1, m, 1); }
#pragma unroll
        for (int n = 0; n < 2; n++) { bfA[n][0] = LB(1, n, 0); bfA[n][1] = LB(1, n, 1); }
        STAGE(0, 2, t2);
        BAR; DS_FENCE;
        MFMA16(afA, bfA, 0, 0);
        BAR;
#pragma unroll
        for (int m = 0; m < 4; m++) { afB[m][0] = LA(1, 4 + m, 0); afB[m][1] = LA(1, 4 + m, 1); }
        STAGE(0, 3, t2);
        BAR; DS_FENCE;
        MFMA16(afB, bfA, 4, 0);
        BAR;
#pragma unroll
        for (int n = 0; n < 2; n++) { bfB[n][0] = LB(1, 2 + n, 0); bfB[n][1] = LB(1, 2 + n, 1); }
        STAGE(1, 0, t3);
        BAR; DS_FENCE;
        MFMA16(afA, bfB, 0, 2);
        BAR;
        STAGE(1, 1, t3);
        BAR;
        MFMA16(afB, bfB, 4, 2);
        asm volatile("s_waitcnt vmcnt(4)" ::: "memory");
        BAR;
        __builtin_amdgcn_sched_barrier(0);
    }

    asm volatile("s_waitcnt vmcnt(0) lgkmcnt(0)" ::: "memory");

    const int crow0 = rowBase + wr * 128 + fq * 4;
    const int ccol0 = colBase + wc * 64 + fr;

    if constexpr (EPI == 2) {
        float* lsum = (float*)out1;
        unsigned short* dst = (unsigned short*)out0 + (long long)tz * sOz;
#pragma unroll
        for (int m = 0; m < 8; m++) {
#pragma unroll
            for (int j = 0; j < 4; j++) {
                const int row = crow0 + m * 16 + j;
                float rs = 0.f;
#pragma unroll
                for (int n = 0; n < 4; n++) {
                    const int col = ccol0 + n * 16;
                    const float p = __expf(acc[m][n][j] * scale);
                    const unsigned short us = f2bf(p);
                    dst[(long long)row * N + col] = us;
                    rs += bf2f(us);
                }
                rs += __shfl_xor(rs, 1); rs += __shfl_xor(rs, 2);
                rs += __shfl_xor(rs, 4); rs += __shfl_xor(rs, 8);
                if (fr == 0) atomicAdd(&lsum[tz * 2048 + row], rs);
            }
        }
    }
    (void)out2; (void)bias;
#undef LA
#undef LB
#undef MFMA16
}

// f32 -> bf16 elementwise (8/thread, vectorized)
__global__ __launch_bounds__(256) void conv_f32_bf16(
    const float* __restrict__ in, unsigned short* __restrict__ out, int n8)
{
    for (int i = blockIdx.x * blockDim.x + threadIdx.x; i < n8;
         i += gridDim.x * blockDim.x) {
        const float4 a = ((const float4*)in)[2 * i];
        const float4 b = ((const float4*)in)[2 * i + 1];
        u16x8 o;
        o[0] = f2bf(a.x); o[1] = f2bf(a.y); o[2] = f2bf(a.z); o[3] = f2bf(a.w);
        o[4] = f2bf(b.x); o[5] = f2bf(b.y); o[6] = f2bf(b.z); o[7] = f2bf(b.w);
        ((u16x8*)out)[i] = o;
    }
}

// w1v[j][h] = bf16(W1[j][2048+h])   (strided slice convert, no transpose)
__global__ __launch_bounds__(256) void conv_w1v(
    const float* __restrict__ W1, unsigned short* __restrict__ w1v)
{
    const int i = blockIdx.x * 256 + threadIdx.x;    // 0..131071
    const int j = i >> 7, hh = (i & 127) * 8;
    const float4 a = *(const float4*)&W1[(long long)j * 3072 + 2048 + hh];
    const float4 b = *(const float4*)&W1[(long long)j * 3072 + 2048 + hh + 4];
    u16x8 o;
    o[0] = f2bf(a.x); o[1] = f2bf(a.y); o[2] = f2bf(a.z); o[3] = f2bf(a.w);
    o[4] = f2bf(b.x); o[5] = f2bf(b.y); o[6] = f2bf(b.z); o[7] = f2bf(b.w);
    *(u16x8*)&w1v[(long long)j * 1024 + hh] = o;
}

// bu2[i] = b2[i] + sum_h b1v[h] * w2t[i][h]   (w2t = W2^T bf16)
__global__ __launch_bounds__(256) void bias_bu2(
    const float* __restrict__ b1, const unsigned short* __restrict__ w2t,
    const float* __restrict__ b2, float* __restrict__ bu2)
{
    const int i = blockIdx.x * 256 + threadIdx.x;    // 0..1023
    float s = b2[i];
    for (int h8 = 0; h8 < 128; ++h8) {
        const u16x8 wv = *(const u16x8*)&w2t[(long long)i * 1024 + h8 * 8];
#pragma unroll
        for (int e = 0; e < 8; ++e)
            s += b1[2048 + h8 * 8 + e] * bf2f(wv[e]);
    }
    bu2[i] = s;
}

// out[cols][rows] (bf16) = transpose(in[rows][cols] f32)
__global__ __launch_bounds__(256) void tconv_f32_bf16(
    const float* __restrict__ in, unsigned short* __restrict__ out,
    int rows, int cols)
{
    __shared__ float t[32][33];
    const int c0 = blockIdx.x * 32, r0 = blockIdx.y * 32;
    const int tx = threadIdx.x & 31, ty = threadIdx.x >> 5;
#pragma unroll
    for (int i = 0; i < 4; i++)
        t[ty + 8 * i][tx] = in[(long long)(r0 + ty + 8 * i) * cols + c0 + tx];
    __syncthreads();
#pragma unroll
    for (int i = 0; i < 4; i++)
        out[(long long)(c0 + ty + 8 * i) * rows + r0 + tx] = f2bf(t[tx][ty + 8 * i]);
}

extern "C" void kernel_launch(void* const* d_in, const int* in_sizes, int n_in,
                              void* d_out, int out_size, void* d_ws, size_t ws_size,
                              hipStream_t stream)
{
    (void)in_sizes; (void)n_in; (void)out_size; (void)ws_size;
    const float* x  = (const float*)d_in[0];
    const float* W1 = (const float*)d_in[1];
    const float* b1 = (const float*)d_in[2];
    const float* W2 = (const float*)d_in[3];
    const float* b2 = (const float*)d_in[4];
    float* out = (float*)d_out;

    char* ws = (char*)d_ws;
    size_t off = 0;
    auto alloc = [&](size_t bytes) {
        void* p = ws + off;
        off += (bytes + 255) & ~(size_t)255;
        return p;
    };
    unsigned short* xbf = (unsigned short*)alloc((size_t)BS_ * D_ * 2);
    unsigned short* w1t = (unsigned short*)alloc((size_t)N3H * D_ * 2);
    unsigned short* w2t = (unsigned short*)alloc((size_t)H_ * H_ * 2);
    unsigned short* w1v = (unsigned short*)alloc((size_t)D_ * H_ * 2);
    unsigned short* q   = (unsigned short*)alloc((size_t)BS_ * H_ * 2);
    unsigned short* k   = (unsigned short*)alloc((size_t)BS_ * H_ * 2);
    unsigned short* ut  = (unsigned short*)alloc((size_t)BS_ * H_ * 2);
    unsigned short* sc  = (unsigned short*)alloc((size_t)B_ * S_ * S_ * 2);
    float*          lsum = (float*)alloc((size_t)BS_ * 4);
    float*          bu2  = (float*)alloc((size_t)H_ * 4);

    const float scale = 0.022097086912079608f;  // (2*D)^-0.5 = 1/sqrt(2048)

    hipMemsetAsync(lsum, 0, (size_t)BS_ * 4, stream);

    conv_f32_bf16<<<dim3(2048), dim3(256), 0, stream>>>(x, xbf, BS_ * D_ / 8);
    tconv_f32_bf16<<<dim3(N3H / 32, D_ / 32), dim3(256), 0, stream>>>(W1, w1t, D_, N3H);
    tconv_f32_bf16<<<dim3(H_ / 32, H_ / 32), dim3(256), 0, stream>>>(W2, w2t, H_, H_);
    conv_w1v<<<dim3(512), dim3(256), 0, stream>>>(W1, w1v);

    // wu = (W1v @ W2)^T = w2t @ w1v^T  [1024,1024] bf16, written INTO w1t
    // rows 2048..3071 (replaces W1v^T so QKV produces u = x@(W1v W2) directly)
    gemm3b<1, 0><<<dim3(64), dim3(256), 0, stream>>>(
        w2t, w1v, 8, 8, 1024, 1024, 0LL, 0LL, 0LL,
        w1t + (size_t)2048 * 1024, nullptr, nullptr, nullptr, 1.0f);

    // bu2 = b1v @ W2 + b2  (bias moved past the softmax average: sum P/l = 1)
    bias_bu2<<<dim3(4), dim3(256), 0, stream>>>(b1, w2t, b2, bu2);

    // QKV: q,k (+b1) and ut (transposed u, no bias).  1536 tiles.
    gemm3b<0, 1><<<dim3(1536), dim3(256), 0, stream>>>(
        xbf, w1t, 24, 64, N3H, D_, 0LL, 0LL, 0LL, q, k, ut, b1, 1.0f);

    // P~[b] = exp((q[b] @ k[b]^T) * scale) bf16 + per-row l atomics.
    gemm256<2><<<dim3(256), dim3(512), 0, stream>>>(
        q, k, 8, 8, S_, H_, (long long)S_ * H_, (long long)S_ * H_,
        (long long)S_ * S_, sc, lsum, nullptr, nullptr, scale);

    // out[b] = (P~[b] @ ut[b]^T) / l + bu2   [2048,1024] f32 — final output
    gemm3b<5, 1><<<dim3(512), dim3(256), 0, stream>>>(
        sc, ut, 8, 16, H_, S_, (long long)S_ * S_, (long long)H_ * S_,
        (long long)S_ * H_, out, bu2, nullptr, lsum, 1.0f);
}

// Round 10
// 189.932 us; speedup vs baseline: 1.1312x; 1.1312x over previous
//
#include <hip/hip_runtime.h>
#include <hip/hip_bf16.h>
#include <stdint.h>

#define B_  4
#define S_  2048
#define D_  1024
#define H_  1024
#define BS_ (B_*S_)    // 8192
#define N3H (3*H_)     // 3072

typedef __bf16 bf16x8 __attribute__((ext_vector_type(8)));
typedef float  f32x4  __attribute__((ext_vector_type(4)));
typedef unsigned short u16x8 __attribute__((ext_vector_type(8)));
typedef unsigned short u16x4 __attribute__((ext_vector_type(4)));

__device__ __forceinline__ unsigned short f2bf(float x) {
    unsigned u = __float_as_uint(x);
    return (unsigned short)((u + 0x7FFFu + ((u >> 16) & 1u)) >> 16);  // RNE
}
__device__ __forceinline__ float bf2f(unsigned short h) {
    return __uint_as_float(((unsigned)h) << 16);
}

__device__ __forceinline__ void gload_lds16(const void* g, void* l) {
    __builtin_amdgcn_global_load_lds(
        (const __attribute__((address_space(1))) void*)g,
        (__attribute__((address_space(3))) void*)l, 16, 0, 0);
}

#define BAR __builtin_amdgcn_s_barrier()
#define DS_FENCE do { asm volatile("s_waitcnt lgkmcnt(0)" ::: "memory"); \
                      __builtin_amdgcn_sched_barrier(0); } while (0)

// ---------------------------------------------------------------------------
// gemm3b: 128x128-tile bt-GEMM, BK=32, 256 threads (2x2 waves, wave 64x64,
// acc 4x4), triple-buffered 48 KiB LDS, 3 blocks/CU. st_16x32 swizzle.
// Core verified rounds 6-9.  K = loop length, Kst = row stride (K != Kst for
// split-K chunks).
// EPI 0: QKV split: q,k (+bias b1); u-segment (cols 2048+) written TRANSPOSED.
// EPI 5: FINAL: f32 out = acc / l[row] + bu2[col]  (l via `bias`, bu2 via out1)
// EPI 6: f32 partial store (split-K wu), chunk selected by tz via sOz.
// SWZ 0: tile=bid; SWZ 1: XCD-chunked + 2D suborder.
// ---------------------------------------------------------------------------
template<int EPI, int SWZ>
__global__ __launch_bounds__(256, 3) void gemm3b(
    const unsigned short* __restrict__ A,
    const unsigned short* __restrict__ Bm,
    int NXt, int NYt, int N, int K, int Kst,
    long long sAz, long long sBz, long long sOz,
    void* __restrict__ out0, void* __restrict__ out1, void* __restrict__ out2,
    const float* __restrict__ bias, float scale)
{
    __shared__ __align__(16) char lds[3 * 16384];

    const int bid = (int)blockIdx.x;
    int tile;
    if constexpr (SWZ) {
        const int nt_g = (int)gridDim.x;
        const int C = nt_g >> 3;
        const int c = bid >> 3;
        const int xcd = bid & 7;
        const int qq = c >> 2;
        const int txl = qq % NXt;
        const int rest = (c & 3) + 4 * (qq / NXt);
        tile = xcd * C + rest * NXt + txl;
    } else {
        tile = bid;
    }
    const int tx = tile % NXt;
    const int rest2 = tile / NXt;
    const int ty = rest2 % NYt;
    const int tz = rest2 / NYt;

    const unsigned short* Ab = A  + (long long)tz * sAz;
    const unsigned short* Bb = Bm + (long long)tz * sBz;
    const int rowBase = ty * 128;
    const int colBase = tx * 128;
    const int tid = threadIdx.x;
    const int w = tid >> 6, l = tid & 63;
    const int wr = w >> 1, wc = w & 1;          // 2M x 2N waves
    const int fr = l & 15, fq = l >> 4;

    // staging source decode (inverse st_16x32 swizzle)
    int sr[2], scl[2];
#pragma unroll
    for (int j = 0; j < 2; j++) {
        int o  = j * 4096 + tid * 16;
        int st = o >> 10;
        int wi = o & 1023;
        wi ^= ((wi >> 9) & 1) << 5;
        sr[j]  = st * 16 + (wi >> 6);
        scl[j] = (wi & 63) >> 1;
    }

    auto STAGE_A = [&](char* buf, int t) {
        const unsigned short* base = Ab + (long long)rowBase * Kst + t * 32;
#pragma unroll
        for (int j = 0; j < 2; j++)
            gload_lds16(base + (long long)sr[j] * Kst + scl[j],
                        buf + j * 4096 + w * 1024);
    };
    auto STAGE_B = [&](char* buf, int t) {
        const unsigned short* base = Bb + (long long)colBase * Kst + t * 32;
#pragma unroll
        for (int j = 0; j < 2; j++)
            gload_lds16(base + (long long)sr[j] * Kst + scl[j],
                        buf + 8192 + j * 4096 + w * 1024);
    };

    const int abase = (fr * 64 + fq * 16) ^ ((fr & 8) << 2);

    f32x4 acc[4][4];
#pragma unroll
    for (int m = 0; m < 4; m++)
#pragma unroll
        for (int n = 0; n < 4; n++) acc[m][n] = (f32x4){0.f, 0.f, 0.f, 0.f};

    const int NT = K >> 5;

    STAGE_A(lds, 0); STAGE_B(lds, 0);
    STAGE_A(lds + 16384, 1); STAGE_B(lds + 16384, 1);
    asm volatile("s_waitcnt vmcnt(4)" ::: "memory");
    BAR;
    __builtin_amdgcn_sched_barrier(0);

    bf16x8 af[4], bf[4];

    for (int t = 0; t < NT; ++t) {
        const char* bc = lds + (t % 3) * 16384;
        char* bs = lds + ((t + 2) % 3) * 16384;
        int ts = t + 2; if (ts >= NT) ts -= NT;

#pragma unroll
        for (int m = 0; m < 4; m++)
            af[m] = *(const bf16x8*)(bc + (wr * 4 + m) * 1024 + abase);
#pragma unroll
        for (int n = 0; n < 4; n++)
            bf[n] = *(const bf16x8*)(bc + 8192 + (wc * 4 + n) * 1024 + abase);
        STAGE_A(bs, ts); STAGE_B(bs, ts);
        BAR; DS_FENCE;
        __builtin_amdgcn_s_setprio(1);
#pragma unroll
        for (int m = 0; m < 4; m++)
#pragma unroll
            for (int n = 0; n < 4; n++)
                acc[m][n] = __builtin_amdgcn_mfma_f32_16x16x32_bf16(
                    af[m], bf[n], acc[m][n], 0, 0, 0);
        __builtin_amdgcn_s_setprio(0);
        asm volatile("s_waitcnt vmcnt(4)" ::: "memory");
        BAR;
        __builtin_amdgcn_sched_barrier(0);
    }

    asm volatile("s_waitcnt vmcnt(0) lgkmcnt(0)" ::: "memory");
    BAR;   // all waves' in-flight DMA landed -> LDS reusable below

    const int crow0 = rowBase + wr * 64 + fq * 4;
    const int ccol0 = colBase + wc * 64 + fr;

    if constexpr (EPI == 0) {
        const int seg = colBase >> 10;           // block is column-aligned
        if (seg < 2) {
            unsigned short* dst = (unsigned short*)(seg == 0 ? out0 : out1);
#pragma unroll
            for (int n = 0; n < 4; n++) {
                const int col = ccol0 + n * 16;
                const float bv = bias[col];
                const int scn = col & 1023;
#pragma unroll
                for (int m = 0; m < 4; m++) {
                    const int r0 = crow0 + m * 16;
#pragma unroll
                    for (int j = 0; j < 4; j++)
                        dst[(long long)(r0 + j) * 1024 + scn] = f2bf(acc[m][n][j] + bv);
                }
            }
        } else {
            // u segment: stage into LDS [128][129], write transposed -> ut[b][h][s]
            unsigned short (*T)[129] = (unsigned short(*)[129])lds;
            const int lr0 = wr * 64 + fq * 4;
            const int lc0 = wc * 64 + fr;
#pragma unroll
            for (int n = 0; n < 4; n++) {
                const int lc = lc0 + n * 16;
#pragma unroll
                for (int m = 0; m < 4; m++)
#pragma unroll
                    for (int j = 0; j < 4; j++)
                        T[lr0 + m * 16 + j][lc] = f2bf(acc[m][n][j]);
            }
            BAR;
            const int s_loc = tid & 127, hh = tid >> 7;
            const int b = rowBase >> 11;
            const int s_glob = (rowBase & 2047) + s_loc;
            unsigned short* ut =
                (unsigned short*)out2 + (long long)b * ((long long)S_ * H_);
            const int h0 = (colBase - 2048) + hh * 64;
#pragma unroll 8
            for (int h = 0; h < 64; ++h)
                ut[(long long)(h0 + h) * S_ + s_glob] = T[s_loc][hh * 64 + h];
        }
    } else if constexpr (EPI == 6) {
        // split-K partial: plain f32 store into chunk tz
        float* dst = (float*)out0 + (long long)tz * sOz;
#pragma unroll
        for (int n = 0; n < 4; n++) {
            const int col = ccol0 + n * 16;
#pragma unroll
            for (int m = 0; m < 4; m++) {
                const int r0 = crow0 + m * 16;
#pragma unroll
                for (int j = 0; j < 4; j++)
                    dst[(long long)(r0 + j) * N + col] = acc[m][n][j];
            }
        }
        (void)scale; (void)bias;
    } else {
        // EPI 5: final output: f32 = acc / l[row] + bu2[col]
        float* dst = (float*)out0 + (long long)tz * sOz;
        const float* bu = (const float*)out1;
#pragma unroll
        for (int m = 0; m < 4; m++) {
            float linv[4];
#pragma unroll
            for (int j = 0; j < 4; j++)
                linv[j] = 1.0f / bias[tz * 2048 + crow0 + m * 16 + j];
#pragma unroll
            for (int n = 0; n < 4; n++) {
                const int col = ccol0 + n * 16;
                const float bvv = bu[col];
                const int r0 = crow0 + m * 16;
#pragma unroll
                for (int j = 0; j < 4; j++)
                    dst[(long long)(r0 + j) * N + col] = acc[m][n][j] * linv[j] + bvv;
            }
        }
        (void)scale;
    }
}

// ---------------------------------------------------------------------------
// gemm256: 256x256 8-phase kernel, XCD-chunked 1D grid. EPI=2 epilogue:
// P~ = exp(acc*scale) bf16; per-row l via shfl-reduce + atomicAdd (out1).
// Verified rounds 7-9.
// ---------------------------------------------------------------------------
template<int EPI>
__global__ __launch_bounds__(512, 2) void gemm256(
    const unsigned short* __restrict__ A,
    const unsigned short* __restrict__ Bm,
    int NXt, int NYt, int N, int K,
    long long sAz, long long sBz, long long sOz,
    void* __restrict__ out0, void* __restrict__ out1, void* __restrict__ out2,
    const float* __restrict__ bias, float scale)
{
    __shared__ __align__(16) char lds[131072];

    const int nt_g = (int)gridDim.x;
    const int bid = (int)blockIdx.x;
    const int C = nt_g >> 3;
    const int c = bid >> 3;
    const int xcd = bid & 7;
    const int qq = c >> 2;
    const int txl = qq % NXt;
    const int rest = (c & 3) + 4 * (qq / NXt);
    const int tile = xcd * C + rest * NXt + txl;
    const int tx = tile % NXt;
    const int rest2 = tile / NXt;
    const int ty = rest2 % NYt;
    const int tz = rest2 / NYt;

    const unsigned short* Ab = A  + (long long)tz * sAz;
    const unsigned short* Bb = Bm + (long long)tz * sBz;
    const int rowBase = ty * 256;
    const int colBase = tx * 256;
    const int tid = threadIdx.x;
    const int w = tid >> 6, l = tid & 63;
    const int wr = w >> 2, wc = w & 3;
    const int fr = l & 15, fq = l >> 4;

    int sr[2], scl[2];
#pragma unroll
    for (int j = 0; j < 2; j++) {
        int o  = j * 8192 + tid * 16;
        int st = o >> 10;
        int wi = o & 1023;
        wi ^= ((wi >> 9) & 1) << 5;
        sr[j]  = (st >> 1) * 16 + (wi >> 6);
        scl[j] = (st & 1) * 32 + ((wi & 63) >> 1);
    }

    auto STAGE = [&](int buf, int which, int tile_) {
        const unsigned short* mat = (which < 2) ? Ab : Bb;
        const int rt0 = ((which < 2) ? rowBase : colBase) + (which & 1) * 128;
        char* dst = lds + buf * 65536 + (which >> 1) * 32768
                        + (which & 1) * 16384 + w * 1024;
        const int k0 = tile_ * 64;
#pragma unroll
        for (int j = 0; j < 2; j++) {
            const unsigned short* src =
                mat + (long long)(rt0 + sr[j]) * K + k0 + scl[j];
            gload_lds16(src, dst + j * 8192);
        }
    };

    const int abase = (fr * 64 + fq * 16) ^ ((fr & 8) << 2);
    const char* Ah[2] = { lds + wr * 16384, lds + 65536 + wr * 16384 };
    const char* Bh[2] = { lds + 32768 + (wc >> 1) * 16384,
                          lds + 98304 + (wc >> 1) * 16384 };
    const int bn0 = (wc & 1) * 8192;

#define LA(b, m, kk) (*(const bf16x8*)(Ah[b] + (m)*2048 + (kk)*1024 + abase))
#define LB(b, n, kk) (*(const bf16x8*)(Bh[b] + bn0 + (n)*2048 + (kk)*1024 + abase))
#define MFMA16(AF, BF, MOFF, NOFF) do { \
    __builtin_amdgcn_s_setprio(1); \
    _Pragma("unroll") for (int m_ = 0; m_ < 4; m_++) \
    _Pragma("unroll") for (int n_ = 0; n_ < 2; n_++) \
    _Pragma("unroll") for (int k_ = 0; k_ < 2; k_++) \
        acc[(MOFF)+m_][(NOFF)+n_] = __builtin_amdgcn_mfma_f32_16x16x32_bf16( \
            AF[m_][k_], BF[n_][k_], acc[(MOFF)+m_][(NOFF)+n_], 0, 0, 0); \
    __builtin_amdgcn_s_setprio(0); } while (0)

    f32x4 acc[8][4];
#pragma unroll
    for (int m = 0; m < 8; m++)
#pragma unroll
        for (int n = 0; n < 4; n++) acc[m][n] = (f32x4){0.f, 0.f, 0.f, 0.f};

    const int NT = K >> 6;

    STAGE(0, 0, 0); STAGE(0, 1, 0); STAGE(0, 2, 0); STAGE(0, 3, 0);
    STAGE(1, 0, 1); STAGE(1, 1, 1);
    asm volatile("s_waitcnt vmcnt(4)" ::: "memory");
    BAR;
    __builtin_amdgcn_sched_barrier(0);

    bf16x8 afA[4][2], afB[4][2], bfA[2][2], bfB[2][2];

    for (int i = 0; i < NT / 2; i++) {
        const int t1 = 2 * i + 1;
        int t2 = 2 * i + 2; if (t2 >= NT) t2 -= NT;
        int t3 = 2 * i + 3; if (t3 >= NT) t3 -= NT;

#pragma unroll
        for (int m = 0; m < 4; m++) { afA[m][0] = LA(0, m, 0); afA[m][1] = LA(0, m, 1); }
#pragma unroll
        for (int n = 0; n < 2; n++) { bfA[n][0] = LB(0, n, 0); bfA[n][1] = LB(0, n, 1); }
        STAGE(1, 2, t1);
        BAR; DS_FENCE;
        MFMA16(afA, bfA, 0, 0);
        BAR;
#pragma unroll
        for (int m = 0; m < 4; m++) { afB[m][0] = LA(0, 4 + m, 0); afB[m][1] = LA(0, 4 + m, 1); }
        STAGE(1, 3, t1);
        BAR; DS_FENCE;
        MFMA16(afB, bfA, 4, 0);
        BAR;
#pragma unroll
        for (int n = 0; n < 2; n++) { bfB[n][0] = LB(0, 2 + n, 0); bfB[n][1] = LB(0, 2 + n, 1); }
        STAGE(0, 0, t2);
        BAR; DS_FENCE;
        MFMA16(afA, bfB, 0, 2);
        BAR;
        STAGE(0, 1, t2);
        BAR;
        MFMA16(afB, bfB, 4, 2);
        asm volatile("s_waitcnt vmcnt(4)" ::: "memory");
        BAR;
        __builtin_amdgcn_sched_barrier(0);

#pragma unroll
        for (int m = 0; m < 4; m++) { afA[m][0] = LA(1, m, 0); afA[m][1] = LA(1, m, 1); }
#pragma unroll
        for (int n = 0; n < 2; n++) { bfA[n][0] = LB(1, n, 0); bfA[n][1] = LB(1, n, 1); }
        STAGE(0, 2, t2);
        BAR; DS_FENCE;
        MFMA16(afA, bfA, 0, 0);
        BAR;
#pragma unroll
        for (int m = 0; m < 4; m++) { afB[m][0] = LA(1, 4 + m, 0); afB[m][1] = LA(1, 4 + m, 1); }
        STAGE(0, 3, t2);
        BAR; DS_FENCE;
        MFMA16(afB, bfA, 4, 0);
        BAR;
#pragma unroll
        for (int n = 0; n < 2; n++) { bfB[n][0] = LB(1, 2 + n, 0); bfB[n][1] = LB(1, 2 + n, 1); }
        STAGE(1, 0, t3);
        BAR; DS_FENCE;
        MFMA16(afA, bfB, 0, 2);
        BAR;
        STAGE(1, 1, t3);
        BAR;
        MFMA16(afB, bfB, 4, 2);
        asm volatile("s_waitcnt vmcnt(4)" ::: "memory");
        BAR;
        __builtin_amdgcn_sched_barrier(0);
    }

    asm volatile("s_waitcnt vmcnt(0) lgkmcnt(0)" ::: "memory");

    const int crow0 = rowBase + wr * 128 + fq * 4;
    const int ccol0 = colBase + wc * 64 + fr;

    if constexpr (EPI == 2) {
        float* lsum = (float*)out1;
        unsigned short* dst = (unsigned short*)out0 + (long long)tz * sOz;
#pragma unroll
        for (int m = 0; m < 8; m++) {
#pragma unroll
            for (int j = 0; j < 4; j++) {
                const int row = crow0 + m * 16 + j;
                float rs = 0.f;
#pragma unroll
                for (int n = 0; n < 4; n++) {
                    const int col = ccol0 + n * 16;
                    const float p = __expf(acc[m][n][j] * scale);
                    const unsigned short us = f2bf(p);
                    dst[(long long)row * N + col] = us;
                    rs += bf2f(us);
                }
                rs += __shfl_xor(rs, 1); rs += __shfl_xor(rs, 2);
                rs += __shfl_xor(rs, 4); rs += __shfl_xor(rs, 8);
                if (fr == 0) atomicAdd(&lsum[tz * 2048 + row], rs);
            }
        }
    }
    (void)out2; (void)bias;
#undef LA
#undef LB
#undef MFMA16
}

// f32 -> bf16 elementwise (8/thread, vectorized)
__global__ __launch_bounds__(256) void conv_f32_bf16(
    const float* __restrict__ in, unsigned short* __restrict__ out, int n8)
{
    for (int i = blockIdx.x * blockDim.x + threadIdx.x; i < n8;
         i += gridDim.x * blockDim.x) {
        const float4 a = ((const float4*)in)[2 * i];
        const float4 b = ((const float4*)in)[2 * i + 1];
        u16x8 o;
        o[0] = f2bf(a.x); o[1] = f2bf(a.y); o[2] = f2bf(a.z); o[3] = f2bf(a.w);
        o[4] = f2bf(b.x); o[5] = f2bf(b.y); o[6] = f2bf(b.z); o[7] = f2bf(b.w);
        ((u16x8*)out)[i] = o;
    }
}

// w1v[j][h] = bf16(W1[j][2048+h])   (strided slice convert, no transpose)
__global__ __launch_bounds__(256) void conv_w1v(
    const float* __restrict__ W1, unsigned short* __restrict__ w1v)
{
    const int i = blockIdx.x * 256 + threadIdx.x;    // 0..131071
    const int j = i >> 7, hh = (i & 127) * 8;
    const float4 a = *(const float4*)&W1[(long long)j * 3072 + 2048 + hh];
    const float4 b = *(const float4*)&W1[(long long)j * 3072 + 2048 + hh + 4];
    u16x8 o;
    o[0] = f2bf(a.x); o[1] = f2bf(a.y); o[2] = f2bf(a.z); o[3] = f2bf(a.w);
    o[4] = f2bf(b.x); o[5] = f2bf(b.y); o[6] = f2bf(b.z); o[7] = f2bf(b.w);
    *(u16x8*)&w1v[(long long)j * 1024 + hh] = o;
}

// wu[n][d] = bf16(sum_c part[c][n][d]) -> written into w1t v-rows
__global__ __launch_bounds__(256) void wu_reduce(
    const float* __restrict__ part, unsigned short* __restrict__ dst)
{
    const int i = blockIdx.x * 256 + threadIdx.x;    // 0..262143 (4 elems each)
    f32x4 s = *(const f32x4*)&part[(long long)i * 4];
#pragma unroll
    for (int c = 1; c < 4; c++) {
        const f32x4 p = *(const f32x4*)&part[(long long)c * 1048576 + (long long)i * 4];
        s[0] += p[0]; s[1] += p[1]; s[2] += p[2]; s[3] += p[3];
    }
    u16x4 o;
    o[0] = f2bf(s[0]); o[1] = f2bf(s[1]); o[2] = f2bf(s[2]); o[3] = f2bf(s[3]);
    *(u16x4*)&dst[(long long)i * 4] = o;
}

// bu2[i] = b2[i] + sum_h b1[2048+h] * w2t[i][h]  — one block per output col
__global__ __launch_bounds__(256) void bias_bu2(
    const float* __restrict__ b1, const unsigned short* __restrict__ w2t,
    const float* __restrict__ b2, float* __restrict__ bu2)
{
    const int i = blockIdx.x;                        // 0..1023
    const int t = threadIdx.x;
    const u16x4 wv = *(const u16x4*)&w2t[(long long)i * 1024 + t * 4];
    const float4 bv = *(const float4*)&b1[2048 + t * 4];
    float s = bv.x * bf2f(wv[0]) + bv.y * bf2f(wv[1])
            + bv.z * bf2f(wv[2]) + bv.w * bf2f(wv[3]);
    for (int o = 32; o; o >>= 1) s += __shfl_xor(s, o);
    __shared__ float red[4];
    if ((t & 63) == 0) red[t >> 6] = s;
    __syncthreads();
    if (t == 0) bu2[i] = red[0] + red[1] + red[2] + red[3] + b2[i];
}

// out[cols][rows] (bf16) = transpose(in[rows][cols] f32)
__global__ __launch_bounds__(256) void tconv_f32_bf16(
    const float* __restrict__ in, unsigned short* __restrict__ out,
    int rows, int cols)
{
    __shared__ float t[32][33];
    const int c0 = blockIdx.x * 32, r0 = blockIdx.y * 32;
    const int tx = threadIdx.x & 31, ty = threadIdx.x >> 5;
#pragma unroll
    for (int i = 0; i < 4; i++)
        t[ty + 8 * i][tx] = in[(long long)(r0 + ty + 8 * i) * cols + c0 + tx];
    __syncthreads();
#pragma unroll
    for (int i = 0; i < 4; i++)
        out[(long long)(c0 + ty + 8 * i) * rows + r0 + tx] = f2bf(t[tx][ty + 8 * i]);
}

extern "C" void kernel_launch(void* const* d_in, const int* in_sizes, int n_in,
                              void* d_out, int out_size, void* d_ws, size_t ws_size,
                              hipStream_t stream)
{
    (void)in_sizes; (void)n_in; (void)out_size; (void)ws_size;
    const float* x  = (const float*)d_in[0];
    const float* W1 = (const float*)d_in[1];
    const float* b1 = (const float*)d_in[2];
    const float* W2 = (const float*)d_in[3];
    const float* b2 = (const float*)d_in[4];
    float* out = (float*)d_out;

    char* ws = (char*)d_ws;
    size_t off = 0;
    auto alloc = [&](size_t bytes) {
        void* p = ws + off;
        off += (bytes + 255) & ~(size_t)255;
        return p;
    };
    // ws budget: 16+6+2+2+16+16+16+64 MB ≈ 138.7 MB — same as rounds 7/8
    // (round 9's separate 16.8 MB `part` overflowed ws -> post-timing
    //  divergence; `part` now ALIASES sc, which is dead until gemm256).
    unsigned short* xbf = (unsigned short*)alloc((size_t)BS_ * D_ * 2);
    unsigned short* w1t = (unsigned short*)alloc((size_t)N3H * D_ * 2);
    unsigned short* w2t = (unsigned short*)alloc((size_t)H_ * H_ * 2);
    unsigned short* w1v = (unsigned short*)alloc((size_t)D_ * H_ * 2);
    unsigned short* q   = (unsigned short*)alloc((size_t)BS_ * H_ * 2);
    unsigned short* k   = (unsigned short*)alloc((size_t)BS_ * H_ * 2);
    unsigned short* ut  = (unsigned short*)alloc((size_t)BS_ * H_ * 2);
    unsigned short* sc  = (unsigned short*)alloc((size_t)B_ * S_ * S_ * 2);
    float*          lsum = (float*)alloc((size_t)BS_ * 4);
    float*          bu2  = (float*)alloc((size_t)H_ * 4);
    float*          part = (float*)sc;   // 16 MB of sc's 64 MB; dead by gemm256

    const float scale = 0.022097086912079608f;  // (2*D)^-0.5 = 1/sqrt(2048)

    hipMemsetAsync(lsum, 0, (size_t)BS_ * 4, stream);

    conv_f32_bf16<<<dim3(2048), dim3(256), 0, stream>>>(x, xbf, BS_ * D_ / 8);
    // only q,k columns (v-rows of w1t get overwritten by wu_reduce)
    tconv_f32_bf16<<<dim3(64, 32), dim3(256), 0, stream>>>(W1, w1t, D_, N3H);
    tconv_f32_bf16<<<dim3(32, 32), dim3(256), 0, stream>>>(W2, w2t, H_, H_);
    conv_w1v<<<dim3(512), dim3(256), 0, stream>>>(W1, w1v);

    // wu = w2t @ w1v^T  [1024,1024], split-K x4: 256 blocks (full chip).
    // part[c][n][d] = sum_{h in chunk c} w2t[n][h]*w1v[d][h]
    gemm3b<6, 0><<<dim3(256), dim3(256), 0, stream>>>(
        w2t, w1v, 8, 8, 1024, 256, 1024, 256LL, 256LL, (long long)H_ * H_,
        part, nullptr, nullptr, nullptr, 1.0f);
    wu_reduce<<<dim3(1024), dim3(256), 0, stream>>>(part, w1t + (size_t)2048 * 1024);

    // bu2 = b1v @ W2 + b2  (bias moved past softmax: sum P/l = 1)
    bias_bu2<<<dim3(1024), dim3(256), 0, stream>>>(b1, w2t, b2, bu2);

    // QKV: q,k (+b1) and ut (transposed u).  1536 tiles.
    gemm3b<0, 1><<<dim3(1536), dim3(256), 0, stream>>>(
        xbf, w1t, 24, 64, N3H, D_, D_, 0LL, 0LL, 0LL, q, k, ut, b1, 1.0f);

    // P~[b] = exp((q[b] @ k[b]^T) * scale) bf16 + per-row l atomics.
    // (writes sc, overwriting the dead `part` region)
    gemm256<2><<<dim3(256), dim3(512), 0, stream>>>(
        q, k, 8, 8, S_, H_, (long long)S_ * H_, (long long)S_ * H_,
        (long long)S_ * S_, sc, lsum, nullptr, nullptr, scale);

    // out[b] = (P~[b] @ ut[b]^T) / l + bu2   [2048,1024] f32 — final output
    gemm3b<5, 1><<<dim3(512), dim3(256), 0, stream>>>(
        sc, ut, 8, 16, H_, S_, S_, (long long)S_ * S_, (long long)H_ * S_,
        (long long)S_ * H_, out, bu2, nullptr, lsum, 1.0f);
}